// Round 12
// baseline (32.208 us; speedup 1.0000x reference)
//
#include <hip/hip_runtime.h>
#include <float.h>

#define B_TOK 256
#define N_OUT 512
#define K_IN  1024

#define KSPLIT 16
#define KC     (K_IN / KSPLIT)   // 64 k per block
#define BT     16                // b rows per block (4 per wave)
#define NT     64                // n per block (1 per lane)

// ---------------- Stage 1 ----------------
// R5 interior verbatim; only occupancy changed: KC 128->64 (16KB LDS),
// KSPLIT 8->16 -> 2048 blocks = 8 blocks/CU = 32 waves/CU (HW max),
// __launch_bounds__(256,8) caps VGPR at 64 (measured 44 for this interior).
// Per 4k-iter/lane: 1 swizzled ds_read_b128 (guide G4 attn pattern) +
// 4 wave-uniform s_load float4 -> 16 products x 4 b rows = 32 VALU.
__global__ __launch_bounds__(256, 8)
void mam_stage1(const float* __restrict__ x, const float* __restrict__ w,
                float* __restrict__ pmx, float* __restrict__ pmn) {
    __shared__ float ws[NT * KC];   // 16 KB

    const int tid = threadIdx.x;
    const int b0  = blockIdx.x * BT;
    const int n0  = blockIdx.y * NT;
    const int kc  = blockIdx.z * KC;

    // ---- stage w[n0..+63][kc..+63] -> LDS (swizzled 16B chunks) ----
    // thread t: row r = t>>2, chunks c = (t&3)+4j (j<4): 4 consecutive lanes
    // read one contiguous 64B line. slot = c ^ (r&7) (bijective, G4 pattern).
    {
        const int r  = tid >> 2;
        const int cb = tid & 3;
        const float* gsrc = w + (size_t)(n0 + r) * K_IN + kc;
#pragma unroll
        for (int j = 0; j < 4; ++j) {
            const int c = cb + 4 * j;
            const float4 v = *reinterpret_cast<const float4*>(gsrc + c * 4);
            *reinterpret_cast<float4*>(&ws[r * KC + ((c ^ (r & 7)) << 2)]) = v;
        }
    }
    __syncthreads();

    // ---- compute: lane = one n; wave = 4 b rows; x wave-uniform -> s_load ----
    const int wv = __builtin_amdgcn_readfirstlane(tid >> 6);  // 0..3, SGPR
    const int ln = tid & 63;
    const float* xb0 = x + (size_t)(b0 + wv * 4 + 0) * K_IN + kc;
    const float* xb1 = x + (size_t)(b0 + wv * 4 + 1) * K_IN + kc;
    const float* xb2 = x + (size_t)(b0 + wv * 4 + 2) * K_IN + kc;
    const float* xb3 = x + (size_t)(b0 + wv * 4 + 3) * K_IN + kc;

    float mx0 = -FLT_MAX, mx1 = -FLT_MAX, mx2 = -FLT_MAX, mx3 = -FLT_MAX;
    float mn0 =  FLT_MAX, mn1 =  FLT_MAX, mn2 =  FLT_MAX, mn3 =  FLT_MAX;

    const int swz = ln & 7;
#pragma unroll 4
    for (int c = 0; c < KC / 4; ++c) {            // 16 iters of 4 k
        const float4 wk = *reinterpret_cast<const float4*>(
            &ws[ln * KC + ((c ^ swz) << 2)]);
        const float4 x0 = *reinterpret_cast<const float4*>(xb0 + c * 4);
        const float4 x1 = *reinterpret_cast<const float4*>(xb1 + c * 4);
        const float4 x2 = *reinterpret_cast<const float4*>(xb2 + c * 4);
        const float4 x3 = *reinterpret_cast<const float4*>(xb3 + c * 4);

        {   const float p0 = x0.x * wk.x, p1 = x0.y * wk.y, p2 = x0.z * wk.z, p3 = x0.w * wk.w;
            mx0 = fmaxf(fmaxf(mx0, p0), p1); mx0 = fmaxf(fmaxf(mx0, p2), p3);   // v_max3
            mn0 = fminf(fminf(mn0, p0), p1); mn0 = fminf(fminf(mn0, p2), p3); }
        {   const float p0 = x1.x * wk.x, p1 = x1.y * wk.y, p2 = x1.z * wk.z, p3 = x1.w * wk.w;
            mx1 = fmaxf(fmaxf(mx1, p0), p1); mx1 = fmaxf(fmaxf(mx1, p2), p3);
            mn1 = fminf(fminf(mn1, p0), p1); mn1 = fminf(fminf(mn1, p2), p3); }
        {   const float p0 = x2.x * wk.x, p1 = x2.y * wk.y, p2 = x2.z * wk.z, p3 = x2.w * wk.w;
            mx2 = fmaxf(fmaxf(mx2, p0), p1); mx2 = fmaxf(fmaxf(mx2, p2), p3);
            mn2 = fminf(fminf(mn2, p0), p1); mn2 = fminf(fminf(mn2, p2), p3); }
        {   const float p0 = x3.x * wk.x, p1 = x3.y * wk.y, p2 = x3.z * wk.z, p3 = x3.w * wk.w;
            mx3 = fmaxf(fmaxf(mx3, p0), p1); mx3 = fmaxf(fmaxf(mx3, p2), p3);
            mn3 = fminf(fminf(mn3, p0), p1); mn3 = fminf(fminf(mn3, p2), p3); }
    }

    // ---- write this block's partial rows (coalesced 256B per row) ----
    const size_t plane = (size_t)B_TOK * N_OUT;
    const size_t base  = (size_t)blockIdx.z * plane
                       + (size_t)(b0 + wv * 4) * N_OUT + n0 + ln;
    pmx[base + 0 * N_OUT] = mx0;  pmn[base + 0 * N_OUT] = mn0;
    pmx[base + 1 * N_OUT] = mx1;  pmn[base + 1 * N_OUT] = mn1;
    pmx[base + 2 * N_OUT] = mx2;  pmn[base + 2 * N_OUT] = mn2;
    pmx[base + 3 * N_OUT] = mx3;  pmn[base + 3 * N_OUT] = mn3;
}

// ---------------- Stage 2: combine 16 planes + bias ----------------
__global__ __launch_bounds__(256)
void mam_stage2(const float* __restrict__ pmx, const float* __restrict__ pmn,
                const float* __restrict__ bias, float* __restrict__ out) {
    const size_t i4 = ((size_t)blockIdx.x * 256 + threadIdx.x) * 4;
    const size_t plane = (size_t)B_TOK * N_OUT;
    float4 MX = *reinterpret_cast<const float4*>(pmx + i4);
    float4 MN = *reinterpret_cast<const float4*>(pmn + i4);
#pragma unroll
    for (int p = 1; p < KSPLIT; ++p) {
        const float4 a = *reinterpret_cast<const float4*>(pmx + (size_t)p * plane + i4);
        const float4 d = *reinterpret_cast<const float4*>(pmn + (size_t)p * plane + i4);
        MX.x = fmaxf(MX.x, a.x); MX.y = fmaxf(MX.y, a.y);
        MX.z = fmaxf(MX.z, a.z); MX.w = fmaxf(MX.w, a.w);
        MN.x = fminf(MN.x, d.x); MN.y = fminf(MN.y, d.y);
        MN.z = fminf(MN.z, d.z); MN.w = fminf(MN.w, d.w);
    }
    const float4 bb = *reinterpret_cast<const float4*>(bias + (i4 & (N_OUT - 1)));
    float4 o;
    o.x = MX.x + MN.x + bb.x; o.y = MX.y + MN.y + bb.y;
    o.z = MX.z + MN.z + bb.z; o.w = MX.w + MN.w + bb.w;
    *reinterpret_cast<float4*>(out + i4) = o;
}

// ---------------- Fallback (workspace too small) ----------------
__global__ __launch_bounds__(256)
void mam_simple(const float* __restrict__ x, const float* __restrict__ w,
                const float* __restrict__ bias, float* __restrict__ out) {
    const int idx = blockIdx.x * 256 + threadIdx.x;
    const int b = idx / N_OUT, n = idx % N_OUT;
    const float* xr = x + (size_t)b * K_IN;
    const float* wr = w + (size_t)n * K_IN;
    float mx = -FLT_MAX, mn = FLT_MAX;
#pragma unroll 4
    for (int k = 0; k < K_IN; k += 4) {
        const float4 xv = *reinterpret_cast<const float4*>(xr + k);
        const float4 wv = *reinterpret_cast<const float4*>(wr + k);
        const float p0 = xv.x * wv.x, p1 = xv.y * wv.y;
        const float p2 = xv.z * wv.z, p3 = xv.w * wv.w;
        mx = fmaxf(fmaxf(mx, p0), p1);
        mx = fmaxf(fmaxf(mx, p2), p3);
        mn = fminf(fminf(mn, p0), p1);
        mn = fminf(fminf(mn, p2), p3);
    }
    out[idx] = mx + mn + bias[n];
}

extern "C" void kernel_launch(void* const* d_in, const int* in_sizes, int n_in,
                              void* d_out, int out_size, void* d_ws, size_t ws_size,
                              hipStream_t stream) {
    const float* x    = (const float*)d_in[0];   // [256,1024]
    const float* w    = (const float*)d_in[1];   // [512,1024]
    const float* bias = (const float*)d_in[2];   // [512]
    float* out = (float*)d_out;                  // [256,512] f32

    const size_t plane = (size_t)B_TOK * N_OUT;
    const size_t need  = 2 * (size_t)KSPLIT * plane * sizeof(float);  // 16.8 MB

    if (ws_size >= need) {
        float* pmx = (float*)d_ws;
        float* pmn = pmx + (size_t)KSPLIT * plane;
        mam_stage1<<<dim3(B_TOK / BT, N_OUT / NT, KSPLIT), 256, 0, stream>>>(x, w, pmx, pmn);
        mam_stage2<<<(int)(plane / 4 / 256), 256, 0, stream>>>(pmx, pmn, bias, out);
    } else {
        mam_simple<<<(B_TOK * N_OUT) / 256, 256, 0, stream>>>(x, w, bias, out);
    }
}

// Round 13
// 28.287 us; speedup vs baseline: 1.1386x; 1.1386x over previous
//
#include <hip/hip_runtime.h>
#include <float.h>

#define B_TOK 256
#define N_OUT 512
#define K_IN  1024

#define KSPLIT 8
#define KC     (K_IN / KSPLIT)   // 128 k per block
#define BT     16                // b rows per block (4 per wave)
#define NT     64                // n per block (1 per lane)

// ---------------- Stage 1 ----------------
// R5 verbatim EXCEPT the x path: wave id is NOT readfirstlane'd, so x addresses
// are not provably wave-uniform -> compiler emits per-lane global_load_dwordx4
// (all lanes same address = single L1 line per instr; block x set = 8KB, L1-fit).
// Result: x waits on vmcnt, w ds_read waits on lgkmcnt -- independent counters,
// partial-wait pipelining instead of the s_load/ds_read shared-lgkmcnt full
// drains (gfx9: scalar loads complete out-of-order -> lgkmcnt(0) before use).
__global__ __launch_bounds__(256)
void mam_stage1(const float* __restrict__ x, const float* __restrict__ w,
                float* __restrict__ pmx, float* __restrict__ pmn) {
    __shared__ float ws[NT * KC];   // 32 KB

    const int tid = threadIdx.x;
    const int b0  = blockIdx.x * BT;
    const int n0  = blockIdx.y * NT;
    const int kc  = blockIdx.z * KC;

    // ---- stage w[n0..+63][kc..+127] -> LDS (swizzled 16B chunks) ----
    // thread t: row r = t>>2, chunks c = (t&3)+4j: 4 consecutive lanes read one
    // contiguous 64B line; ds_write slot = c ^ (r&7) (bijective per row).
    {
        const int r  = tid >> 2;
        const int cb = tid & 3;
        const float* gsrc = w + (size_t)(n0 + r) * K_IN + kc;
#pragma unroll
        for (int j = 0; j < 8; ++j) {
            const int c = cb + 4 * j;
            const float4 v = *reinterpret_cast<const float4*>(gsrc + c * 4);
            *reinterpret_cast<float4*>(&ws[r * KC + ((c ^ (r & 7)) << 2)]) = v;
        }
    }
    __syncthreads();

    // ---- compute: lane = one n; wave = 4 b rows ----
    const int wvv = tid >> 6;   // deliberately NOT readfirstlane: keep in VGPR
    const int ln  = tid & 63;
    const float* xb0 = x + (size_t)(b0 + wvv * 4 + 0) * K_IN + kc;
    const float* xb1 = x + (size_t)(b0 + wvv * 4 + 1) * K_IN + kc;
    const float* xb2 = x + (size_t)(b0 + wvv * 4 + 2) * K_IN + kc;
    const float* xb3 = x + (size_t)(b0 + wvv * 4 + 3) * K_IN + kc;

    float mx0 = -FLT_MAX, mx1 = -FLT_MAX, mx2 = -FLT_MAX, mx3 = -FLT_MAX;
    float mn0 =  FLT_MAX, mn1 =  FLT_MAX, mn2 =  FLT_MAX, mn3 =  FLT_MAX;

    const int swz = ln & 7;
#pragma unroll 4
    for (int c = 0; c < KC / 4; ++c) {            // 32 iters of 4 k
        const float4 wk = *reinterpret_cast<const float4*>(
            &ws[ln * KC + ((c ^ swz) << 2)]);     // conflict-free ds_read_b128
        const float4 x0 = *reinterpret_cast<const float4*>(xb0 + c * 4);  // VMEM
        const float4 x1 = *reinterpret_cast<const float4*>(xb1 + c * 4);  // broadcast
        const float4 x2 = *reinterpret_cast<const float4*>(xb2 + c * 4);  // (1 line
        const float4 x3 = *reinterpret_cast<const float4*>(xb3 + c * 4);  //  /instr)

        {   const float p0 = x0.x * wk.x, p1 = x0.y * wk.y, p2 = x0.z * wk.z, p3 = x0.w * wk.w;
            mx0 = fmaxf(fmaxf(mx0, p0), p1); mx0 = fmaxf(fmaxf(mx0, p2), p3);   // v_max3
            mn0 = fminf(fminf(mn0, p0), p1); mn0 = fminf(fminf(mn0, p2), p3); }
        {   const float p0 = x1.x * wk.x, p1 = x1.y * wk.y, p2 = x1.z * wk.z, p3 = x1.w * wk.w;
            mx1 = fmaxf(fmaxf(mx1, p0), p1); mx1 = fmaxf(fmaxf(mx1, p2), p3);
            mn1 = fminf(fminf(mn1, p0), p1); mn1 = fminf(fminf(mn1, p2), p3); }
        {   const float p0 = x2.x * wk.x, p1 = x2.y * wk.y, p2 = x2.z * wk.z, p3 = x2.w * wk.w;
            mx2 = fmaxf(fmaxf(mx2, p0), p1); mx2 = fmaxf(fmaxf(mx2, p2), p3);
            mn2 = fminf(fminf(mn2, p0), p1); mn2 = fminf(fminf(mn2, p2), p3); }
        {   const float p0 = x3.x * wk.x, p1 = x3.y * wk.y, p2 = x3.z * wk.z, p3 = x3.w * wk.w;
            mx3 = fmaxf(fmaxf(mx3, p0), p1); mx3 = fmaxf(fmaxf(mx3, p2), p3);
            mn3 = fminf(fminf(mn3, p0), p1); mn3 = fminf(fminf(mn3, p2), p3); }
    }

    // ---- write this block's partial rows (coalesced 256B per row) ----
    const size_t plane = (size_t)B_TOK * N_OUT;
    const size_t base  = (size_t)blockIdx.z * plane
                       + (size_t)(b0 + wvv * 4) * N_OUT + n0 + ln;
    pmx[base + 0 * N_OUT] = mx0;  pmn[base + 0 * N_OUT] = mn0;
    pmx[base + 1 * N_OUT] = mx1;  pmn[base + 1 * N_OUT] = mn1;
    pmx[base + 2 * N_OUT] = mx2;  pmn[base + 2 * N_OUT] = mn2;
    pmx[base + 3 * N_OUT] = mx3;  pmn[base + 3 * N_OUT] = mn3;
}

// ---------------- Stage 2: combine 8 planes + bias ----------------
__global__ __launch_bounds__(256)
void mam_stage2(const float* __restrict__ pmx, const float* __restrict__ pmn,
                const float* __restrict__ bias, float* __restrict__ out) {
    const size_t i4 = ((size_t)blockIdx.x * 256 + threadIdx.x) * 4;
    const size_t plane = (size_t)B_TOK * N_OUT;
    float4 MX = *reinterpret_cast<const float4*>(pmx + i4);
    float4 MN = *reinterpret_cast<const float4*>(pmn + i4);
#pragma unroll
    for (int p = 1; p < KSPLIT; ++p) {
        const float4 a = *reinterpret_cast<const float4*>(pmx + (size_t)p * plane + i4);
        const float4 d = *reinterpret_cast<const float4*>(pmn + (size_t)p * plane + i4);
        MX.x = fmaxf(MX.x, a.x); MX.y = fmaxf(MX.y, a.y);
        MX.z = fmaxf(MX.z, a.z); MX.w = fmaxf(MX.w, a.w);
        MN.x = fminf(MN.x, d.x); MN.y = fminf(MN.y, d.y);
        MN.z = fminf(MN.z, d.z); MN.w = fminf(MN.w, d.w);
    }
    const float4 bb = *reinterpret_cast<const float4*>(bias + (i4 & (N_OUT - 1)));
    float4 o;
    o.x = MX.x + MN.x + bb.x; o.y = MX.y + MN.y + bb.y;
    o.z = MX.z + MN.z + bb.z; o.w = MX.w + MN.w + bb.w;
    *reinterpret_cast<float4*>(out + i4) = o;
}

// ---------------- Fallback (workspace too small) ----------------
__global__ __launch_bounds__(256)
void mam_simple(const float* __restrict__ x, const float* __restrict__ w,
                const float* __restrict__ bias, float* __restrict__ out) {
    const int idx = blockIdx.x * 256 + threadIdx.x;
    const int b = idx / N_OUT, n = idx % N_OUT;
    const float* xr = x + (size_t)b * K_IN;
    const float* wr = w + (size_t)n * K_IN;
    float mx = -FLT_MAX, mn = FLT_MAX;
#pragma unroll 4
    for (int k = 0; k < K_IN; k += 4) {
        const float4 xv = *reinterpret_cast<const float4*>(xr + k);
        const float4 wv = *reinterpret_cast<const float4*>(wr + k);
        const float p0 = xv.x * wv.x, p1 = xv.y * wv.y;
        const float p2 = xv.z * wv.z, p3 = xv.w * wv.w;
        mx = fmaxf(fmaxf(mx, p0), p1);
        mx = fmaxf(fmaxf(mx, p2), p3);
        mn = fminf(fminf(mn, p0), p1);
        mn = fminf(fminf(mn, p2), p3);
    }
    out[idx] = mx + mn + bias[n];
}

extern "C" void kernel_launch(void* const* d_in, const int* in_sizes, int n_in,
                              void* d_out, int out_size, void* d_ws, size_t ws_size,
                              hipStream_t stream) {
    const float* x    = (const float*)d_in[0];   // [256,1024]
    const float* w    = (const float*)d_in[1];   // [512,1024]
    const float* bias = (const float*)d_in[2];   // [512]
    float* out = (float*)d_out;                  // [256,512] f32

    const size_t plane = (size_t)B_TOK * N_OUT;
    const size_t need  = 2 * (size_t)KSPLIT * plane * sizeof(float);  // 8 MB

    if (ws_size >= need) {
        float* pmx = (float*)d_ws;
        float* pmn = pmx + (size_t)KSPLIT * plane;
        mam_stage1<<<dim3(B_TOK / BT, N_OUT / NT, KSPLIT), 256, 0, stream>>>(x, w, pmx, pmn);
        mam_stage2<<<(int)(plane / 4 / 256), 256, 0, stream>>>(pmx, pmn, bias, out);
    } else {
        mam_simple<<<(B_TOK * N_OUT) / 256, 256, 0, stream>>>(x, w, bias, out);
    }
}